// Round 11
// baseline (470.058 us; speedup 1.0000x reference)
//
#include <hip/hip_runtime.h>
#include <hip/hip_bf16.h>
#include <stdint.h>
#include <math.h>

typedef __bf16 bf16;
typedef __bf16 bf16x8 __attribute__((ext_vector_type(8)));
typedef __bf16 bf16x4 __attribute__((ext_vector_type(4)));
typedef float  f32x4  __attribute__((ext_vector_type(4)));
typedef float  f32x16 __attribute__((ext_vector_type(16)));
typedef int    i32x4  __attribute__((ext_vector_type(4)));
typedef int    i32x16 __attribute__((ext_vector_type(16)));

#define AS_GLOBAL __attribute__((address_space(1)))
#define AS_LDS    __attribute__((address_space(3)))

__device__ __forceinline__ void gload_lds16(const void* g, void* l) {
    __builtin_amdgcn_global_load_lds((const AS_GLOBAL uint32_t*)g,
                                     (AS_LDS uint32_t*)l, 16, 0, 0);
}
__device__ __forceinline__ void cfence() { asm volatile("" ::: "memory"); }
#define BAR()    do { cfence(); __builtin_amdgcn_s_barrier(); cfence(); } while (0)
#define WAITV(n) asm volatile("s_waitcnt vmcnt(" #n ")" ::: "memory")
#define WAITL0() asm volatile("s_waitcnt lgkmcnt(0)" ::: "memory")

#define QSC 36.0f                            // q/k int8 scale
#define QDQ (1.0f / (QSC * QSC * 32.0f))     // logit dequant incl 1/sqrt(1024)

__device__ __forceinline__ int qi8(float f) {
    int q = (int)rintf(f);
    return q > 127 ? 127 : (q < -127 ? -127 : q);
}

// ---------------- convert fp32 -> bf16, 4 elems/thread ----------------
__global__ __launch_bounds__(256) void cvt_f32_to_bf16(const float* __restrict__ in,
                                                       bf16* __restrict__ out, int n4) {
    int i = blockIdx.x * 256 + threadIdx.x;
    if (i >= n4) return;
    const float4* p = (const float4*)in;
    float4 v = p[i];
    bf16x4 o;
    o[0] = (bf16)v.x; o[1] = (bf16)v.y; o[2] = (bf16)v.z; o[3] = (bf16)v.w;
    *(bf16x4*)(out + (size_t)i * 4) = o;
}

// ---------------- zero a float buffer ----------------
__global__ __launch_bounds__(256) void zero_f32(float* __restrict__ p, int n) {
    int i = blockIdx.x * 256 + threadIdx.x;
    if (i < n) p[i] = 0.f;
}

// ---- Q,K panels of QKV (bf16, ld=3072) -> int8 (scale 36), 8 elems/thread ----
__global__ __launch_bounds__(256) void cvt_qk_i8(const bf16* __restrict__ QKV,
                                                 int8_t* __restrict__ Qi8,
                                                 int8_t* __restrict__ Ki8) {
    int i = blockIdx.x * 256 + threadIdx.x;
    int base = i * 8;
    int row = base >> 11;
    int c = base & 2047;
    bf16x8 v = *(const bf16x8*)(QKV + (size_t)row * 3072 + c);
    uint32_t w0 = 0, w1 = 0;
    #pragma unroll
    for (int j = 0; j < 4; ++j) w0 |= (uint32_t)(qi8((float)v[j] * QSC) & 0xff) << (8 * j);
    #pragma unroll
    for (int j = 0; j < 4; ++j) w1 |= (uint32_t)(qi8((float)v[j + 4] * QSC) & 0xff) << (8 * j);
    int8_t* dst = (c < 1024) ? (Qi8 + (size_t)row * 1024 + c)
                             : (Ki8 + (size_t)row * 1024 + (c - 1024));
    uint2 pk; pk.x = w0; pk.y = w1;
    *(uint2*)dst = pk;
}

// ====== int8 QK^T -> bf16 E = exp(acc/41472), + fused row-sum atomics ======
// r10-verified geometry/schedule. Epilogue adds: per-lane ni-sum of bf16-rounded
// E, 5-step shfl_xor butterfly over the 32 same-row lanes (halves hold distinct
// rows), 2 lanes/wave atomicAdd 16 rows each into pre-zeroed sums[].
__global__ __launch_bounds__(512, 2) void gemmEi8(const int8_t* __restrict__ A,
                                                  const int8_t* __restrict__ B,
                                                  bf16* __restrict__ E,
                                                  float* __restrict__ sums,
                                                  int K, int ld, int ldc, int nbn) {
    __shared__ char smem[131072];   // A dbuf 2x32KB @0 | B dbuf 2x32KB @65536

    const int tid  = threadIdx.x;
    const int lane = tid & 63;
    const int wave = tid >> 6;
    const int wr   = wave >> 2;           // 0..1
    const int wc   = wave & 3;            // 0..3

    const int cpx = gridDim.x >> 3;
    const int swz = ((int)blockIdx.x & 7) * cpx + ((int)blockIdx.x >> 3);
    const int bm = swz / nbn, bn = swz % nbn;
    const int NT = K >> 7;                // 8

    const int r0 = tid >> 3;
    const int c0 = ((tid & 7) ^ (r0 & 7)) << 4;     // inv-swizzled byte col
    const int8_t* Abase = A + (size_t)(bm * 256 + r0) * ld + c0;
    const int8_t* Bbase = B + (size_t)(bn * 256 + r0) * ld + c0;

    auto stA = [&](int t, int h) {
        char* d = smem + ((t & 1) << 15) + (h << 14) + (tid << 4);
        gload_lds16(Abase + ((size_t)(h * 128)     ) * ld + t * 128, d);
        gload_lds16(Abase + ((size_t)(h * 128) + 64) * ld + t * 128, d + 8192);
    };
    auto stB = [&](int t, int h) {
        char* d = smem + 65536 + ((t & 1) << 15) + (h << 14) + (tid << 4);
        gload_lds16(Bbase + ((size_t)(h * 128)     ) * ld + t * 128, d);
        gload_lds16(Bbase + ((size_t)(h * 128) + 64) * ld + t * 128, d + 8192);
    };
    auto rdFrag = [&](const char* hbase, int rr, int kk) -> i32x4 {
        int slot = ((kk << 1) + (lane >> 5)) ^ (rr & 7);
        return *(const i32x4*)(hbase + rr * 128 + (slot << 4));
    };
    auto rdA = [&](int t, int m, int kk) -> i32x4 {
        const char* hb = smem + ((t & 1) << 15) + (wr << 14);
        return rdFrag(hb, m * 32 + (lane & 31), kk);
    };
    auto rdB = [&](int t, int n, int kk) -> i32x4 {
        int gr = wc * 64 + n * 32 + (lane & 31);
        const char* hb = smem + 65536 + ((t & 1) << 15) + ((gr >> 7) << 14);
        return rdFrag(hb, gr & 127, kk);
    };

    i32x16 acc[4][2] = {};
    i32x4 a[4][4], b[2][4];

#define MM16(MO) \
    _Pragma("unroll") for (int m_ = 0; m_ < 2; ++m_) \
    _Pragma("unroll") for (int n_ = 0; n_ < 2; ++n_) \
    _Pragma("unroll") for (int k_ = 0; k_ < 4; ++k_) \
        acc[m_ + MO][n_] = __builtin_amdgcn_mfma_i32_32x32x32_i8( \
            a[m_ + MO][k_], b[n_][k_], acc[m_ + MO][n_], 0, 0, 0);

    stA(0, 0); stA(0, 1); stB(0, 0); stB(0, 1);
    stA(1, 0); stA(1, 1); stB(1, 0);
    WAITV(6);
    BAR();

    for (int t = 0; t < NT; ++t) {
        if (t + 1 < NT) stB(t + 1, 1);
        #pragma unroll
        for (int m_ = 0; m_ < 4; ++m_)
            #pragma unroll
            for (int k_ = 0; k_ < 4; ++k_) a[m_][k_] = rdA(t, m_, k_);
        #pragma unroll
        for (int n_ = 0; n_ < 2; ++n_)
            #pragma unroll
            for (int k_ = 0; k_ < 4; ++k_) b[n_][k_] = rdB(t, n_, k_);
        __builtin_amdgcn_s_setprio(1);
        MM16(0);
        __builtin_amdgcn_s_setprio(0);
        WAITL0();
        BAR();
        if (t + 2 < NT) { stA(t + 2, 0); stA(t + 2, 1); stB(t + 2, 0); }
        __builtin_amdgcn_s_setprio(1);
        MM16(2);
        __builtin_amdgcn_s_setprio(0);
        if (t + 2 < NT)      { WAITV(6); }
        else if (t + 1 < NT) { WAITV(0); }
        BAR();
    }
#undef MM16

    // epilogue: E = exp(acc * QDQ) + fused row-sums
    const int crow0 = bm * 256 + wr * 128 + 4 * (lane >> 5);
    const int ccol0 = bn * 256 + wc * 64 + (lane & 31);
    #pragma unroll
    for (int mi = 0; mi < 4; ++mi) {
        float rs[16];
        #pragma unroll
        for (int r = 0; r < 16; ++r) {
            int row = crow0 + mi * 32 + (r & 3) + 8 * (r >> 2);
            float e0 = __expf((float)acc[mi][0][r] * QDQ);
            float e1 = __expf((float)acc[mi][1][r] * QDQ);
            bf16 b0 = (bf16)e0, b1 = (bf16)e1;
            E[(size_t)row * ldc + ccol0]      = b0;
            E[(size_t)row * ldc + ccol0 + 32] = b1;
            rs[r] = (float)b0 + (float)b1;
        }
        #pragma unroll
        for (int r = 0; r < 16; ++r)
            #pragma unroll
            for (int off = 1; off <= 16; off <<= 1)
                rs[r] += __shfl_xor(rs[r], off);
        if ((lane & 31) == 0) {
            #pragma unroll
            for (int r = 0; r < 16; ++r) {
                int row = crow0 + mi * 32 + (r & 3) + 8 * (r >> 2);
                atomicAdd(&sums[row], rs[r]);
            }
        }
    }
}

// ====== PV GEMM: 32x32x16 bf16 MFMA on the verified i8 skeleton, split-K=2 ======
// C[M,1024](+partial) = A[M,K] * B[1024,K]^T, BM=BN=256, BK=64 bf16 (=128B rows),
// 512 thr = 8 waves (2M x 4N), wave tile 128x64 = 4m x 2n 32x32 tiles x 4 ksteps.
// A/B frag: row = lane&31, k = kstep*16 + (lane>>5)*8 + [0,8) elems -> byte slot
// = (kstep*2 + (lane>>5)) ^ (row&7), identical slot math to gemmEi8 (16B chunks).
// Same 2-window schedule, same XOR swizzle via inverse-swizzled global source.
__global__ __launch_bounds__(512, 2) void gemmPV(const bf16* __restrict__ A,
                                                 const bf16* __restrict__ B,
                                                 float* __restrict__ C,
                                                 float* __restrict__ C2,
                                                 int K, int lda, int ldb, int ldc,
                                                 int nbn) {
    __shared__ char smem[131072];   // A dbuf 2x32KB @0 | B dbuf 2x32KB @65536

    const int tid  = threadIdx.x;
    const int lane = tid & 63;
    const int wave = tid >> 6;
    const int wr   = wave >> 2;
    const int wc   = wave & 3;

    const int cpx = gridDim.x >> 3;
    const int swz = ((int)blockIdx.x & 7) * cpx + ((int)blockIdx.x >> 3);
    int id = swz;
    const int s = id & 1; id >>= 1;
    const int bm = id / nbn, bn = id % nbn;
    const int NT = K >> 6;                // 64
    const size_t koff = (size_t)s * K;
    float* Cp = (s == 1) ? C2 : C;

    const int r0 = tid >> 3;
    const int c0 = ((tid & 7) ^ (r0 & 7)) << 3;     // inv-swizzled col (bf16 elems)
    const bf16* Abase = A + (size_t)(bm * 256 + r0) * lda + c0 + koff;
    const bf16* Bbase = B + (size_t)(bn * 256 + r0) * ldb + c0 + koff;

    auto stA = [&](int t, int h) {
        char* d = smem + ((t & 1) << 15) + (h << 14) + (tid << 4);
        gload_lds16(Abase + ((size_t)(h * 128)     ) * lda + t * 64, d);
        gload_lds16(Abase + ((size_t)(h * 128) + 64) * lda + t * 64, d + 8192);
    };
    auto stB = [&](int t, int h) {
        char* d = smem + 65536 + ((t & 1) << 15) + (h << 14) + (tid << 4);
        gload_lds16(Bbase + ((size_t)(h * 128)     ) * ldb + t * 64, d);
        gload_lds16(Bbase + ((size_t)(h * 128) + 64) * ldb + t * 64, d + 8192);
    };
    auto rdFrag = [&](const char* hbase, int rr, int kk) -> bf16x8 {
        int slot = ((kk << 1) + (lane >> 5)) ^ (rr & 7);
        return *(const bf16x8*)(hbase + rr * 128 + (slot << 4));
    };
    auto rdA = [&](int t, int m, int kk) -> bf16x8 {
        const char* hb = smem + ((t & 1) << 15) + (wr << 14);
        return rdFrag(hb, m * 32 + (lane & 31), kk);
    };
    auto rdB = [&](int t, int n, int kk) -> bf16x8 {
        int gr = wc * 64 + n * 32 + (lane & 31);
        const char* hb = smem + 65536 + ((t & 1) << 15) + ((gr >> 7) << 14);
        return rdFrag(hb, gr & 127, kk);
    };

    f32x16 acc[4][2] = {};
    bf16x8 a[4][4], b[2][4];

#define MM16B(MO) \
    _Pragma("unroll") for (int m_ = 0; m_ < 2; ++m_) \
    _Pragma("unroll") for (int n_ = 0; n_ < 2; ++n_) \
    _Pragma("unroll") for (int k_ = 0; k_ < 4; ++k_) \
        acc[m_ + MO][n_] = __builtin_amdgcn_mfma_f32_32x32x16_bf16( \
            a[m_ + MO][k_], b[n_][k_], acc[m_ + MO][n_], 0, 0, 0);

    stA(0, 0); stA(0, 1); stB(0, 0); stB(0, 1);
    stA(1, 0); stA(1, 1); stB(1, 0);
    WAITV(6);
    BAR();

    for (int t = 0; t < NT; ++t) {
        // ---------- window 1 ----------
        if (t + 1 < NT) stB(t + 1, 1);
        #pragma unroll
        for (int m_ = 0; m_ < 4; ++m_)
            #pragma unroll
            for (int k_ = 0; k_ < 4; ++k_) a[m_][k_] = rdA(t, m_, k_);
        #pragma unroll
        for (int n_ = 0; n_ < 2; ++n_)
            #pragma unroll
            for (int k_ = 0; k_ < 4; ++k_) b[n_][k_] = rdB(t, n_, k_);
        __builtin_amdgcn_s_setprio(1);
        MM16B(0);
        __builtin_amdgcn_s_setprio(0);
        WAITL0();
        BAR();
        // ---------- window 2 ----------
        if (t + 2 < NT) { stA(t + 2, 0); stA(t + 2, 1); stB(t + 2, 0); }
        __builtin_amdgcn_s_setprio(1);
        MM16B(2);
        __builtin_amdgcn_s_setprio(0);
        if (t + 2 < NT)      { WAITV(6); }
        else if (t + 1 < NT) { WAITV(0); }
        BAR();
    }
#undef MM16B

    // epilogue: 32x32 C/D layout, raw f32 acc out
    const int crow0 = bm * 256 + wr * 128 + 4 * (lane >> 5);
    const int ccol0 = bn * 256 + wc * 64 + (lane & 31);
    #pragma unroll
    for (int mi = 0; mi < 4; ++mi)
        #pragma unroll
        for (int ni = 0; ni < 2; ++ni)
            #pragma unroll
            for (int r = 0; r < 16; ++r) {
                int row = crow0 + mi * 32 + (r & 3) + 8 * (r >> 2);
                Cp[(size_t)row * ldc + ccol0 + ni * 32] = acc[mi][ni][r];
            }
}

// ====== 2-window/K-tile bf16 GEMM (r7, verified) — QKV projection ======
template<typename CT, int BN>
__global__ __launch_bounds__(512, 2) void gemmW(const bf16* __restrict__ A,
                                                const bf16* __restrict__ B,
                                                CT* __restrict__ C,
                                                int K, int lda, int ldb, int ldc,
                                                int nbn) {
    constexpr int NBH = BN / 128;
    constexpr int NR  = BN / 64;
    constexpr int NHF = NR / 2;
    __shared__ char smem[65536 + NBH * 32768];

    const int tid  = threadIdx.x;
    const int lane = tid & 63;
    const int wave = tid >> 6;
    const int wr   = wave >> 2;
    const int wc   = wave & 3;
    const int frow = lane & 15;
    const int fg   = lane >> 4;

    const int cpx = gridDim.x >> 3;
    const int swz = ((int)blockIdx.x & 7) * cpx + ((int)blockIdx.x >> 3);
    const int bm = swz / nbn, bn = swz % nbn;
    const int NT = K >> 6;

    const int r0 = tid >> 3;
    const int c0 = ((tid & 7) ^ (r0 & 7)) << 3;
    const bf16* Abase = A + (size_t)(bm * 256 + r0) * lda + c0;
    const bf16* Bbase = B + (size_t)(bn * BN + r0) * ldb + c0;

    auto stA = [&](int t, int h) {
        char* d = smem + ((t & 1) << 15) + (h << 14) + (tid << 4);
        gload_lds16(Abase + ((size_t)(h * 128)      ) * lda + t * 64, d);
        gload_lds16(Abase + ((size_t)(h * 128) + 64 ) * lda + t * 64, d + 8192);
    };
    auto stB = [&](int t, int h) {
        char* d = smem + 65536 + (t & 1) * (NBH * 16384) + (h << 14) + (tid << 4);
        gload_lds16(Bbase + ((size_t)(h * 128)      ) * ldb + t * 64, d);
        gload_lds16(Bbase + ((size_t)(h * 128) + 64 ) * ldb + t * 64, d + 8192);
    };
    auto rdA = [&](int t, int m, int kk) -> bf16x8 {
        int r = m * 16 + frow;
        return *(const bf16x8*)(smem + ((t & 1) << 15) + (wr << 14)
                + r * 128 + ((((kk << 2) + fg) ^ (frow & 7)) << 4));
    };
    auto rdB = [&](int t, int n, int kk) -> bf16x8 {
        int br = wc * (BN / 4) + n * 16 + frow;
        return *(const bf16x8*)(smem + 65536 + (t & 1) * (NBH * 16384) + ((br >> 7) << 14)
                + (br & 127) * 128 + ((((kk << 2) + fg) ^ (frow & 7)) << 4));
    };

    f32x4 acc[8][NR] = {};
    bf16x8 aLo[4][2], aHi[4][2], bLo[NHF][2], bHi[NHF][2];

#define MMQ(MO, NO, AARR, BARR) \
    _Pragma("unroll") for (int m_ = 0; m_ < 4; ++m_) \
    _Pragma("unroll") for (int n_ = 0; n_ < NHF; ++n_) \
    _Pragma("unroll") for (int k_ = 0; k_ < 2; ++k_) \
        acc[m_ + MO][n_ + NO] = __builtin_amdgcn_mfma_f32_16x16x32_bf16( \
            AARR[m_][k_], BARR[n_][k_], acc[m_ + MO][n_ + NO], 0, 0, 0);

    stA(0, 0); stA(0, 1);
    stB(0, 0); if constexpr (NBH == 2) stB(0, 1);
    stA(1, 0); stA(1, 1);
    if constexpr (NBH == 2) { stB(1, 0); WAITV(6); } else { WAITV(4); }
    BAR();

    for (int t = 0; t < NT; ++t) {
        if (t + 1 < NT) stB(t + 1, NBH - 1);
        #pragma unroll
        for (int m_ = 0; m_ < 4; ++m_) { aLo[m_][0] = rdA(t, m_, 0); aLo[m_][1] = rdA(t, m_, 1); }
        #pragma unroll
        for (int n_ = 0; n_ < NHF; ++n_) { bLo[n_][0] = rdB(t, n_, 0); bLo[n_][1] = rdB(t, n_, 1); }
        #pragma unroll
        for (int n_ = 0; n_ < NHF; ++n_) { bHi[n_][0] = rdB(t, NHF + n_, 0); bHi[n_][1] = rdB(t, NHF + n_, 1); }
        #pragma unroll
        for (int m_ = 0; m_ < 4; ++m_) { aHi[m_][0] = rdA(t, 4 + m_, 0); aHi[m_][1] = rdA(t, 4 + m_, 1); }
        __builtin_amdgcn_s_setprio(1);
        MMQ(0, 0, aLo, bLo);
        MMQ(0, NHF, aLo, bHi);
        __builtin_amdgcn_s_setprio(0);
        WAITL0();
        BAR();
        if (t + 2 < NT) {
            stA(t + 2, 0); stA(t + 2, 1);
            if constexpr (NBH == 2) stB(t + 2, 0);
        }
        __builtin_amdgcn_s_setprio(1);
        MMQ(4, NHF, aHi, bHi);
        MMQ(4, 0, aHi, bLo);
        __builtin_amdgcn_s_setprio(0);
        if (t + 2 < NT) {
            if constexpr (NBH == 2) WAITV(6); else WAITV(4);
        } else if (t + 1 < NT) {
            WAITV(0);
        }
        BAR();
    }
#undef MMQ

    const size_t crow0 = (size_t)bm * 256 + wr * 128 + (fg << 2);
    const size_t ccol0 = (size_t)bn * BN + wc * (BN / 4) + frow;
    #pragma unroll
    for (int m = 0; m < 8; ++m)
        #pragma unroll
        for (int n = 0; n < NR; ++n)
            #pragma unroll
            for (int i = 0; i < 4; ++i)
                C[(crow0 + m * 16 + i) * ldc + ccol0 + n * 16] = (CT)(acc[m][n][i]);
}

// ------- out[i] = (out[i] + part[i]) / sums[row], float4 -------
__global__ __launch_bounds__(256) void add_scale(float* __restrict__ out,
                                                 const float* __restrict__ part,
                                                 const float* __restrict__ sums, int n4) {
    int i = blockIdx.x * 256 + threadIdx.x;
    if (i >= n4) return;
    const float sc = 1.0f / sums[i >> 8];
    float4 a = ((const float4*)out)[i];
    float4 b = ((const float4*)part)[i];
    a.x = (a.x + b.x) * sc; a.y = (a.y + b.y) * sc;
    a.z = (a.z + b.z) * sc; a.w = (a.w + b.w) * sc;
    ((float4*)out)[i] = a;
}

// ------- bf16 transpose with input row stride: VT[c][r] = V[r*ld + c] -------
__global__ __launch_bounds__(256) void transpose_bf16(const ushort* __restrict__ V,
                                                      ushort* __restrict__ VT,
                                                      int R, int ld) {
    __shared__ ushort tile[32][33];
    const int tx = threadIdx.x, ty = threadIdx.y;
    const int r0 = blockIdx.y * 32, c0 = blockIdx.x * 32;
    #pragma unroll
    for (int i = 0; i < 32; i += 8)
        tile[ty + i][tx] = V[(size_t)(r0 + ty + i) * ld + c0 + tx];
    __syncthreads();
    #pragma unroll
    for (int i = 0; i < 32; i += 8)
        VT[(size_t)(c0 + ty + i) * R + r0 + tx] = tile[tx][ty + i];
}

extern "C" void kernel_launch(void* const* d_in, const int* in_sizes, int n_in,
                              void* d_out, int out_size, void* d_ws, size_t ws_size,
                              hipStream_t stream) {
    const float* h  = (const float*)d_in[0];
    const float* wq = (const float*)d_in[1];
    const float* wk = (const float*)d_in[2];
    const float* wv = (const float*)d_in[3];
    float* out = (float*)d_out;

    char* ws = (char*)d_ws;
    bf16*   h_bf = (bf16*)(ws);                         // 16 MB [8192 x 1024]
    bf16*   wcat = (bf16*)(ws + (16ull << 20));         //  6 MB [3072 x 1024]
    bf16*   QKV  = (bf16*)(ws + (22ull << 20));         // 48 MB [8192 x 3072]
    bf16*   VT   = (bf16*)(ws + (70ull << 20));         // 16 MB [1024 x 8192]
    bf16*   E    = (bf16*)(ws + (86ull << 20));         // 128 MB [8192 x 8192]
    int8_t* Qi8  = (int8_t*)(ws);                       //  8 MB (h_bf dead post-QKV)
    int8_t* Ki8  = (int8_t*)(ws + (8ull << 20));        //  8 MB
    float*  Pv   = (float*)(ws);                        // 32 MB (Qi8/Ki8 dead by PV)
    float*  sums = (float*)(ws + (33ull << 20));        // 32 KB (QKV dead by then)

    // 1) inputs -> bf16 (weights concatenated [3072,1024])
    cvt_f32_to_bf16<<<8192, 256, 0, stream>>>(h,  h_bf, (8192 * 1024) / 4);
    cvt_f32_to_bf16<<<1024, 256, 0, stream>>>(wq, wcat,               (1024 * 1024) / 4);
    cvt_f32_to_bf16<<<1024, 256, 0, stream>>>(wk, wcat + 1024 * 1024, (1024 * 1024) / 4);
    cvt_f32_to_bf16<<<1024, 256, 0, stream>>>(wv, wcat + 2048 * 1024, (1024 * 1024) / 4);

    // 2) QKV = h @ wcat^T : [8192 x 3072], bf16 GEMM, grid 384
    gemmW<bf16, 256><<<384, 512, 0, stream>>>(h_bf, wcat, QKV,
                                              1024, 1024, 1024, 3072, 12);

    // 3) Q,K -> int8 (scale 36)
    cvt_qk_i8<<<8192, 256, 0, stream>>>(QKV, Qi8, Ki8);

    // 4) VT = V^T, bf16 (V = QKV[:, 2048:3072])
    transpose_bf16<<<dim3(32, 256), dim3(32, 8), 0, stream>>>(
        (const ushort*)(QKV + 2048), (ushort*)VT, 8192, 3072);

    // 5) zero row-sum accumulator (QKV now dead)
    zero_f32<<<32, 256, 0, stream>>>(sums, 8192);

    // 6) E = exp((Qi8 . Ki8)/41472) with fused row-sum atomics, grid 1024
    gemmEi8<<<1024, 512, 0, stream>>>(Qi8, Ki8, E, sums, 1024, 1024, 8192, 32);

    // 7) P = E @ VT^T, 32x32x16 bf16, split-K=2, grid 32m x 4n x 2s = 256
    gemmPV<<<256, 512, 0, stream>>>(E, VT, out, Pv,
                                    4096, 8192, 8192, 1024, 4);

    // 8) out = (P0 + P1) / sums[row]
    add_scale<<<8192, 256, 0, stream>>>(out, Pv, sums, (8192 * 1024) / 4);
}

// Round 12
// 364.588 us; speedup vs baseline: 1.2893x; 1.2893x over previous
//
#include <hip/hip_runtime.h>
#include <hip/hip_bf16.h>
#include <stdint.h>
#include <math.h>

typedef __bf16 bf16;
typedef __bf16 bf16x8 __attribute__((ext_vector_type(8)));
typedef __bf16 bf16x4 __attribute__((ext_vector_type(4)));
typedef float  f32x4  __attribute__((ext_vector_type(4)));
typedef float  f32x16 __attribute__((ext_vector_type(16)));
typedef int    i32x4  __attribute__((ext_vector_type(4)));
typedef int    i32x16 __attribute__((ext_vector_type(16)));

#define AS_GLOBAL __attribute__((address_space(1)))
#define AS_LDS    __attribute__((address_space(3)))

__device__ __forceinline__ void gload_lds16(const void* g, void* l) {
    __builtin_amdgcn_global_load_lds((const AS_GLOBAL uint32_t*)g,
                                     (AS_LDS uint32_t*)l, 16, 0, 0);
}
__device__ __forceinline__ void cfence() { asm volatile("" ::: "memory"); }
#define BAR()    do { cfence(); __builtin_amdgcn_s_barrier(); cfence(); } while (0)
#define WAITV(n) asm volatile("s_waitcnt vmcnt(" #n ")" ::: "memory")
#define WAITL0() asm volatile("s_waitcnt lgkmcnt(0)" ::: "memory")

#define QSC 36.0f                            // q/k int8 scale
#define QDQ (1.0f / (QSC * QSC * 32.0f))     // logit dequant incl 1/sqrt(1024)

__device__ __forceinline__ int qi8(float f) {
    int q = (int)rintf(f);
    return q > 127 ? 127 : (q < -127 ? -127 : q);
}

// ---------------- convert fp32 -> bf16, 4 elems/thread ----------------
__global__ __launch_bounds__(256) void cvt_f32_to_bf16(const float* __restrict__ in,
                                                       bf16* __restrict__ out, int n4) {
    int i = blockIdx.x * 256 + threadIdx.x;
    if (i >= n4) return;
    const float4* p = (const float4*)in;
    float4 v = p[i];
    bf16x4 o;
    o[0] = (bf16)v.x; o[1] = (bf16)v.y; o[2] = (bf16)v.z; o[3] = (bf16)v.w;
    *(bf16x4*)(out + (size_t)i * 4) = o;
}

// ---- Q,K panels of QKV (bf16, ld=3072) -> int8 (scale 36), 8 elems/thread ----
__global__ __launch_bounds__(256) void cvt_qk_i8(const bf16* __restrict__ QKV,
                                                 int8_t* __restrict__ Qi8,
                                                 int8_t* __restrict__ Ki8) {
    int i = blockIdx.x * 256 + threadIdx.x;
    int base = i * 8;
    int row = base >> 11;
    int c = base & 2047;
    bf16x8 v = *(const bf16x8*)(QKV + (size_t)row * 3072 + c);
    uint32_t w0 = 0, w1 = 0;
    #pragma unroll
    for (int j = 0; j < 4; ++j) w0 |= (uint32_t)(qi8((float)v[j] * QSC) & 0xff) << (8 * j);
    #pragma unroll
    for (int j = 0; j < 4; ++j) w1 |= (uint32_t)(qi8((float)v[j + 4] * QSC) & 0xff) << (8 * j);
    int8_t* dst = (c < 1024) ? (Qi8 + (size_t)row * 1024 + c)
                             : (Ki8 + (size_t)row * 1024 + (c - 1024));
    uint2 pk; pk.x = w0; pk.y = w1;
    *(uint2*)dst = pk;
}

// ====== int8 QK^T -> bf16 E = exp(acc/41472). r10-verified (clean epilogue) ======
// 256x256 tile, BK=128 bytes, 512 thr = 8 waves (2M x 4N), wave tile 128x64
// via 32x32x32 i8 MFMA (4m x 2n x 4k). A/B frag: row = lane&31,
// k = (lane>>5)*16 + [0,16) bytes. C/D: col = lane&31,
// row = (reg&3)+8*(reg>>2)+4*(lane>>5).
// 2-window schedule: W1 {stage B1(t+1); 24 ds_reads; 16 MFMA mlo; lgkmcnt(0);
// bar}  W2 {stage A0,A1,B0(t+2); 16 MFMA mhi; vmcnt(6); bar}.
// XOR swizzle 16B-slot ^= (row&7) via inverse-swizzled global source.
// NOTE (r11 lesson): NO cross-lane reduction here — __shfl_xor is ds_bpermute
// (LDS traffic); fused rowsum cost 170 µs + 6.3M bank conflicts. Keep separate.
__global__ __launch_bounds__(512, 2) void gemmEi8(const int8_t* __restrict__ A,
                                                  const int8_t* __restrict__ B,
                                                  bf16* __restrict__ E,
                                                  int K, int ld, int ldc, int nbn) {
    __shared__ char smem[131072];   // A dbuf 2x32KB @0 | B dbuf 2x32KB @65536

    const int tid  = threadIdx.x;
    const int lane = tid & 63;
    const int wave = tid >> 6;
    const int wr   = wave >> 2;           // 0..1
    const int wc   = wave & 3;            // 0..3

    const int cpx = gridDim.x >> 3;
    const int swz = ((int)blockIdx.x & 7) * cpx + ((int)blockIdx.x >> 3);
    const int bm = swz / nbn, bn = swz % nbn;
    const int NT = K >> 7;                // 8

    const int r0 = tid >> 3;
    const int c0 = ((tid & 7) ^ (r0 & 7)) << 4;     // inv-swizzled byte col
    const int8_t* Abase = A + (size_t)(bm * 256 + r0) * ld + c0;
    const int8_t* Bbase = B + (size_t)(bn * 256 + r0) * ld + c0;

    auto stA = [&](int t, int h) {
        char* d = smem + ((t & 1) << 15) + (h << 14) + (tid << 4);
        gload_lds16(Abase + ((size_t)(h * 128)     ) * ld + t * 128, d);
        gload_lds16(Abase + ((size_t)(h * 128) + 64) * ld + t * 128, d + 8192);
    };
    auto stB = [&](int t, int h) {
        char* d = smem + 65536 + ((t & 1) << 15) + (h << 14) + (tid << 4);
        gload_lds16(Bbase + ((size_t)(h * 128)     ) * ld + t * 128, d);
        gload_lds16(Bbase + ((size_t)(h * 128) + 64) * ld + t * 128, d + 8192);
    };
    auto rdFrag = [&](const char* hbase, int rr, int kk) -> i32x4 {
        int slot = ((kk << 1) + (lane >> 5)) ^ (rr & 7);
        return *(const i32x4*)(hbase + rr * 128 + (slot << 4));
    };
    auto rdA = [&](int t, int m, int kk) -> i32x4 {
        const char* hb = smem + ((t & 1) << 15) + (wr << 14);
        return rdFrag(hb, m * 32 + (lane & 31), kk);
    };
    auto rdB = [&](int t, int n, int kk) -> i32x4 {
        int gr = wc * 64 + n * 32 + (lane & 31);
        const char* hb = smem + 65536 + ((t & 1) << 15) + ((gr >> 7) << 14);
        return rdFrag(hb, gr & 127, kk);
    };

    i32x16 acc[4][2] = {};
    i32x4 a[4][4], b[2][4];

#define MM16(MO) \
    _Pragma("unroll") for (int m_ = 0; m_ < 2; ++m_) \
    _Pragma("unroll") for (int n_ = 0; n_ < 2; ++n_) \
    _Pragma("unroll") for (int k_ = 0; k_ < 4; ++k_) \
        acc[m_ + MO][n_] = __builtin_amdgcn_mfma_i32_32x32x32_i8( \
            a[m_ + MO][k_], b[n_][k_], acc[m_ + MO][n_], 0, 0, 0);

    stA(0, 0); stA(0, 1); stB(0, 0); stB(0, 1);
    stA(1, 0); stA(1, 1); stB(1, 0);
    WAITV(6);
    BAR();

    for (int t = 0; t < NT; ++t) {
        if (t + 1 < NT) stB(t + 1, 1);
        #pragma unroll
        for (int m_ = 0; m_ < 4; ++m_)
            #pragma unroll
            for (int k_ = 0; k_ < 4; ++k_) a[m_][k_] = rdA(t, m_, k_);
        #pragma unroll
        for (int n_ = 0; n_ < 2; ++n_)
            #pragma unroll
            for (int k_ = 0; k_ < 4; ++k_) b[n_][k_] = rdB(t, n_, k_);
        __builtin_amdgcn_s_setprio(1);
        MM16(0);
        __builtin_amdgcn_s_setprio(0);
        WAITL0();
        BAR();
        if (t + 2 < NT) { stA(t + 2, 0); stA(t + 2, 1); stB(t + 2, 0); }
        __builtin_amdgcn_s_setprio(1);
        MM16(2);
        __builtin_amdgcn_s_setprio(0);
        if (t + 2 < NT)      { WAITV(6); }
        else if (t + 1 < NT) { WAITV(0); }
        BAR();
    }
#undef MM16

    // epilogue: E = exp(acc * QDQ), bf16, 32x32 C/D layout (clean, r10)
    const int crow0 = bm * 256 + wr * 128 + 4 * (lane >> 5);
    const int ccol0 = bn * 256 + wc * 64 + (lane & 31);
    #pragma unroll
    for (int mi = 0; mi < 4; ++mi)
        #pragma unroll
        for (int ni = 0; ni < 2; ++ni)
            #pragma unroll
            for (int r = 0; r < 16; ++r) {
                int row = crow0 + mi * 32 + (r & 3) + 8 * (r >> 2);
                E[(size_t)row * ldc + ccol0 + ni * 32] =
                    (bf16)__expf((float)acc[mi][ni][r] * QDQ);
            }
}

// ====== PV GEMM: 32x32x16 bf16 MFMA on the verified skeleton, split-K=2 ======
// (validated r11: passed with identical absmax)
__global__ __launch_bounds__(512, 2) void gemmPV(const bf16* __restrict__ A,
                                                 const bf16* __restrict__ B,
                                                 float* __restrict__ C,
                                                 float* __restrict__ C2,
                                                 int K, int lda, int ldb, int ldc,
                                                 int nbn) {
    __shared__ char smem[131072];   // A dbuf 2x32KB @0 | B dbuf 2x32KB @65536

    const int tid  = threadIdx.x;
    const int lane = tid & 63;
    const int wave = tid >> 6;
    const int wr   = wave >> 2;
    const int wc   = wave & 3;

    const int cpx = gridDim.x >> 3;
    const int swz = ((int)blockIdx.x & 7) * cpx + ((int)blockIdx.x >> 3);
    int id = swz;
    const int s = id & 1; id >>= 1;
    const int bm = id / nbn, bn = id % nbn;
    const int NT = K >> 6;                // 64
    const size_t koff = (size_t)s * K;
    float* Cp = (s == 1) ? C2 : C;

    const int r0 = tid >> 3;
    const int c0 = ((tid & 7) ^ (r0 & 7)) << 3;     // inv-swizzled col (bf16 elems)
    const bf16* Abase = A + (size_t)(bm * 256 + r0) * lda + c0 + koff;
    const bf16* Bbase = B + (size_t)(bn * 256 + r0) * ldb + c0 + koff;

    auto stA = [&](int t, int h) {
        char* d = smem + ((t & 1) << 15) + (h << 14) + (tid << 4);
        gload_lds16(Abase + ((size_t)(h * 128)     ) * lda + t * 64, d);
        gload_lds16(Abase + ((size_t)(h * 128) + 64) * lda + t * 64, d + 8192);
    };
    auto stB = [&](int t, int h) {
        char* d = smem + 65536 + ((t & 1) << 15) + (h << 14) + (tid << 4);
        gload_lds16(Bbase + ((size_t)(h * 128)     ) * ldb + t * 64, d);
        gload_lds16(Bbase + ((size_t)(h * 128) + 64) * ldb + t * 64, d + 8192);
    };
    auto rdFrag = [&](const char* hbase, int rr, int kk) -> bf16x8 {
        int slot = ((kk << 1) + (lane >> 5)) ^ (rr & 7);
        return *(const bf16x8*)(hbase + rr * 128 + (slot << 4));
    };
    auto rdA = [&](int t, int m, int kk) -> bf16x8 {
        const char* hb = smem + ((t & 1) << 15) + (wr << 14);
        return rdFrag(hb, m * 32 + (lane & 31), kk);
    };
    auto rdB = [&](int t, int n, int kk) -> bf16x8 {
        int gr = wc * 64 + n * 32 + (lane & 31);
        const char* hb = smem + 65536 + ((t & 1) << 15) + ((gr >> 7) << 14);
        return rdFrag(hb, gr & 127, kk);
    };

    f32x16 acc[4][2] = {};
    bf16x8 a[4][4], b[2][4];

#define MM16B(MO) \
    _Pragma("unroll") for (int m_ = 0; m_ < 2; ++m_) \
    _Pragma("unroll") for (int n_ = 0; n_ < 2; ++n_) \
    _Pragma("unroll") for (int k_ = 0; k_ < 4; ++k_) \
        acc[m_ + MO][n_] = __builtin_amdgcn_mfma_f32_32x32x16_bf16( \
            a[m_ + MO][k_], b[n_][k_], acc[m_ + MO][n_], 0, 0, 0);

    stA(0, 0); stA(0, 1); stB(0, 0); stB(0, 1);
    stA(1, 0); stA(1, 1); stB(1, 0);
    WAITV(6);
    BAR();

    for (int t = 0; t < NT; ++t) {
        if (t + 1 < NT) stB(t + 1, 1);
        #pragma unroll
        for (int m_ = 0; m_ < 4; ++m_)
            #pragma unroll
            for (int k_ = 0; k_ < 4; ++k_) a[m_][k_] = rdA(t, m_, k_);
        #pragma unroll
        for (int n_ = 0; n_ < 2; ++n_)
            #pragma unroll
            for (int k_ = 0; k_ < 4; ++k_) b[n_][k_] = rdB(t, n_, k_);
        __builtin_amdgcn_s_setprio(1);
        MM16B(0);
        __builtin_amdgcn_s_setprio(0);
        WAITL0();
        BAR();
        if (t + 2 < NT) { stA(t + 2, 0); stA(t + 2, 1); stB(t + 2, 0); }
        __builtin_amdgcn_s_setprio(1);
        MM16B(2);
        __builtin_amdgcn_s_setprio(0);
        if (t + 2 < NT)      { WAITV(6); }
        else if (t + 1 < NT) { WAITV(0); }
        BAR();
    }
#undef MM16B

    // epilogue: 32x32 C/D layout, raw f32 acc out
    const int crow0 = bm * 256 + wr * 128 + 4 * (lane >> 5);
    const int ccol0 = bn * 256 + wc * 64 + (lane & 31);
    #pragma unroll
    for (int mi = 0; mi < 4; ++mi)
        #pragma unroll
        for (int ni = 0; ni < 2; ++ni)
            #pragma unroll
            for (int r = 0; r < 16; ++r) {
                int row = crow0 + mi * 32 + (r & 3) + 8 * (r >> 2);
                Cp[(size_t)row * ldc + ccol0 + ni * 32] = acc[mi][ni][r];
            }
}

// ====== 2-window/K-tile bf16 GEMM (r7, verified) — QKV projection ======
template<typename CT, int BN>
__global__ __launch_bounds__(512, 2) void gemmW(const bf16* __restrict__ A,
                                                const bf16* __restrict__ B,
                                                CT* __restrict__ C,
                                                int K, int lda, int ldb, int ldc,
                                                int nbn) {
    constexpr int NBH = BN / 128;
    constexpr int NR  = BN / 64;
    constexpr int NHF = NR / 2;
    __shared__ char smem[65536 + NBH * 32768];

    const int tid  = threadIdx.x;
    const int lane = tid & 63;
    const int wave = tid >> 6;
    const int wr   = wave >> 2;
    const int wc   = wave & 3;
    const int frow = lane & 15;
    const int fg   = lane >> 4;

    const int cpx = gridDim.x >> 3;
    const int swz = ((int)blockIdx.x & 7) * cpx + ((int)blockIdx.x >> 3);
    const int bm = swz / nbn, bn = swz % nbn;
    const int NT = K >> 6;

    const int r0 = tid >> 3;
    const int c0 = ((tid & 7) ^ (r0 & 7)) << 3;
    const bf16* Abase = A + (size_t)(bm * 256 + r0) * lda + c0;
    const bf16* Bbase = B + (size_t)(bn * BN + r0) * ldb + c0;

    auto stA = [&](int t, int h) {
        char* d = smem + ((t & 1) << 15) + (h << 14) + (tid << 4);
        gload_lds16(Abase + ((size_t)(h * 128)      ) * lda + t * 64, d);
        gload_lds16(Abase + ((size_t)(h * 128) + 64 ) * lda + t * 64, d + 8192);
    };
    auto stB = [&](int t, int h) {
        char* d = smem + 65536 + (t & 1) * (NBH * 16384) + (h << 14) + (tid << 4);
        gload_lds16(Bbase + ((size_t)(h * 128)      ) * ldb + t * 64, d);
        gload_lds16(Bbase + ((size_t)(h * 128) + 64 ) * ldb + t * 64, d + 8192);
    };
    auto rdA = [&](int t, int m, int kk) -> bf16x8 {
        int r = m * 16 + frow;
        return *(const bf16x8*)(smem + ((t & 1) << 15) + (wr << 14)
                + r * 128 + ((((kk << 2) + fg) ^ (frow & 7)) << 4));
    };
    auto rdB = [&](int t, int n, int kk) -> bf16x8 {
        int br = wc * (BN / 4) + n * 16 + frow;
        return *(const bf16x8*)(smem + 65536 + (t & 1) * (NBH * 16384) + ((br >> 7) << 14)
                + (br & 127) * 128 + ((((kk << 2) + fg) ^ (frow & 7)) << 4));
    };

    f32x4 acc[8][NR] = {};
    bf16x8 aLo[4][2], aHi[4][2], bLo[NHF][2], bHi[NHF][2];

#define MMQ(MO, NO, AARR, BARR) \
    _Pragma("unroll") for (int m_ = 0; m_ < 4; ++m_) \
    _Pragma("unroll") for (int n_ = 0; n_ < NHF; ++n_) \
    _Pragma("unroll") for (int k_ = 0; k_ < 2; ++k_) \
        acc[m_ + MO][n_ + NO] = __builtin_amdgcn_mfma_f32_16x16x32_bf16( \
            AARR[m_][k_], BARR[n_][k_], acc[m_ + MO][n_ + NO], 0, 0, 0);

    stA(0, 0); stA(0, 1);
    stB(0, 0); if constexpr (NBH == 2) stB(0, 1);
    stA(1, 0); stA(1, 1);
    if constexpr (NBH == 2) { stB(1, 0); WAITV(6); } else { WAITV(4); }
    BAR();

    for (int t = 0; t < NT; ++t) {
        if (t + 1 < NT) stB(t + 1, NBH - 1);
        #pragma unroll
        for (int m_ = 0; m_ < 4; ++m_) { aLo[m_][0] = rdA(t, m_, 0); aLo[m_][1] = rdA(t, m_, 1); }
        #pragma unroll
        for (int n_ = 0; n_ < NHF; ++n_) { bLo[n_][0] = rdB(t, n_, 0); bLo[n_][1] = rdB(t, n_, 1); }
        #pragma unroll
        for (int n_ = 0; n_ < NHF; ++n_) { bHi[n_][0] = rdB(t, NHF + n_, 0); bHi[n_][1] = rdB(t, NHF + n_, 1); }
        #pragma unroll
        for (int m_ = 0; m_ < 4; ++m_) { aHi[m_][0] = rdA(t, 4 + m_, 0); aHi[m_][1] = rdA(t, 4 + m_, 1); }
        __builtin_amdgcn_s_setprio(1);
        MMQ(0, 0, aLo, bLo);
        MMQ(0, NHF, aLo, bHi);
        __builtin_amdgcn_s_setprio(0);
        WAITL0();
        BAR();
        if (t + 2 < NT) {
            stA(t + 2, 0); stA(t + 2, 1);
            if constexpr (NBH == 2) stB(t + 2, 0);
        }
        __builtin_amdgcn_s_setprio(1);
        MMQ(4, NHF, aHi, bHi);
        MMQ(4, 0, aHi, bLo);
        __builtin_amdgcn_s_setprio(0);
        if (t + 2 < NT) {
            if constexpr (NBH == 2) WAITV(6); else WAITV(4);
        } else if (t + 1 < NT) {
            WAITV(0);
        }
        BAR();
    }
#undef MMQ

    const size_t crow0 = (size_t)bm * 256 + wr * 128 + (fg << 2);
    const size_t ccol0 = (size_t)bn * BN + wc * (BN / 4) + frow;
    #pragma unroll
    for (int m = 0; m < 8; ++m)
        #pragma unroll
        for (int n = 0; n < NR; ++n)
            #pragma unroll
            for (int i = 0; i < 4; ++i)
                C[(crow0 + m * 16 + i) * ldc + ccol0 + n * 16] = (CT)(acc[m][n][i]);
}

// ------- rowsum of E [rows x 8192] bf16 -> inv[row] = 1/sum -------
__global__ __launch_bounds__(256) void rowsum_inv(const bf16* __restrict__ E,
                                                  float* __restrict__ inv, int cols) {
    __shared__ float red[4];
    const int tid = threadIdx.x;
    const bf16* er = E + (size_t)blockIdx.x * cols;
    float s = 0.f;
    #pragma unroll
    for (int it = 0; it < 4; ++it) {
        bf16x8 v = *(const bf16x8*)(er + it * 2048 + tid * 8);
        #pragma unroll
        for (int j = 0; j < 8; ++j) s += (float)v[j];
    }
    #pragma unroll
    for (int o = 32; o; o >>= 1) s += __shfl_xor(s, o);
    if ((tid & 63) == 0) red[tid >> 6] = s;
    __syncthreads();
    if (tid == 0) inv[blockIdx.x] = 1.0f / (red[0] + red[1] + red[2] + red[3]);
}

// ------- out[i] = (out[i] + part[i]) * inv[row], float4 -------
__global__ __launch_bounds__(256) void add_scale(float* __restrict__ out,
                                                 const float* __restrict__ part,
                                                 const float* __restrict__ inv, int n4) {
    int i = blockIdx.x * 256 + threadIdx.x;
    if (i >= n4) return;
    const float sc = inv[i >> 8];
    float4 a = ((const float4*)out)[i];
    float4 b = ((const float4*)part)[i];
    a.x = (a.x + b.x) * sc; a.y = (a.y + b.y) * sc;
    a.z = (a.z + b.z) * sc; a.w = (a.w + b.w) * sc;
    ((float4*)out)[i] = a;
}

// ------- bf16 transpose with input row stride: VT[c][r] = V[r*ld + c] -------
__global__ __launch_bounds__(256) void transpose_bf16(const ushort* __restrict__ V,
                                                      ushort* __restrict__ VT,
                                                      int R, int ld) {
    __shared__ ushort tile[32][33];
    const int tx = threadIdx.x, ty = threadIdx.y;
    const int r0 = blockIdx.y * 32, c0 = blockIdx.x * 32;
    #pragma unroll
    for (int i = 0; i < 32; i += 8)
        tile[ty + i][tx] = V[(size_t)(r0 + ty + i) * ld + c0 + tx];
    __syncthreads();
    #pragma unroll
    for (int i = 0; i < 32; i += 8)
        VT[(size_t)(c0 + ty + i) * R + r0 + tx] = tile[tx][ty + i];
}

extern "C" void kernel_launch(void* const* d_in, const int* in_sizes, int n_in,
                              void* d_out, int out_size, void* d_ws, size_t ws_size,
                              hipStream_t stream) {
    const float* h  = (const float*)d_in[0];
    const float* wq = (const float*)d_in[1];
    const float* wk = (const float*)d_in[2];
    const float* wv = (const float*)d_in[3];
    float* out = (float*)d_out;

    char* ws = (char*)d_ws;
    bf16*   h_bf = (bf16*)(ws);                         // 16 MB [8192 x 1024]
    bf16*   wcat = (bf16*)(ws + (16ull << 20));         //  6 MB [3072 x 1024]
    bf16*   QKV  = (bf16*)(ws + (22ull << 20));         // 48 MB [8192 x 3072]
    bf16*   VT   = (bf16*)(ws + (70ull << 20));         // 16 MB [1024 x 8192]
    bf16*   E    = (bf16*)(ws + (86ull << 20));         // 128 MB [8192 x 8192]
    int8_t* Qi8  = (int8_t*)(ws);                       //  8 MB (h_bf dead post-QKV)
    int8_t* Ki8  = (int8_t*)(ws + (8ull << 20));        //  8 MB
    float*  Pv   = (float*)(ws);                        // 32 MB (Qi8/Ki8 dead by PV)
    float*  invp = (float*)(ws + (33ull << 20));        // 32 KB (QKV dead by rowsum)

    // 1) inputs -> bf16 (weights concatenated [3072,1024])
    cvt_f32_to_bf16<<<8192, 256, 0, stream>>>(h,  h_bf, (8192 * 1024) / 4);
    cvt_f32_to_bf16<<<1024, 256, 0, stream>>>(wq, wcat,               (1024 * 1024) / 4);
    cvt_f32_to_bf16<<<1024, 256, 0, stream>>>(wk, wcat + 1024 * 1024, (1024 * 1024) / 4);
    cvt_f32_to_bf16<<<1024, 256, 0, stream>>>(wv, wcat + 2048 * 1024, (1024 * 1024) / 4);

    // 2) QKV = h @ wcat^T : [8192 x 3072], bf16 GEMM, grid 384
    gemmW<bf16, 256><<<384, 512, 0, stream>>>(h_bf, wcat, QKV,
                                              1024, 1024, 1024, 3072, 12);

    // 3) Q,K -> int8 (scale 36)
    cvt_qk_i8<<<8192, 256, 0, stream>>>(QKV, Qi8, Ki8);

    // 4) VT = V^T, bf16 (V = QKV[:, 2048:3072])
    transpose_bf16<<<dim3(32, 256), dim3(32, 8), 0, stream>>>(
        (const ushort*)(QKV + 2048), (ushort*)VT, 8192, 3072);

    // 5) E = exp((Qi8 . Ki8)/41472), int8 MFMA, bf16 out, grid 1024
    gemmEi8<<<1024, 512, 0, stream>>>(Qi8, Ki8, E, 1024, 1024, 8192, 32);

    // 6) inv[row] = 1 / rowsum(E)
    rowsum_inv<<<8192, 256, 0, stream>>>(E, invp, 8192);

    // 7) P = E @ VT^T, 32x32x16 bf16, split-K=2, grid 32m x 4n x 2s = 256
    gemmPV<<<256, 512, 0, stream>>>(E, VT, out, Pv,
                                    4096, 8192, 8192, 1024, 4);

    // 8) out = (P0 + P1) * inv[row]
    add_scale<<<8192, 256, 0, stream>>>(out, Pv, invp, (8192 * 1024) / 4);
}

// Round 13
// 337.868 us; speedup vs baseline: 1.3912x; 1.0791x over previous
//
#include <hip/hip_runtime.h>
#include <hip/hip_bf16.h>
#include <stdint.h>
#include <math.h>

typedef __bf16 bf16;
typedef __bf16 bf16x8 __attribute__((ext_vector_type(8)));
typedef __bf16 bf16x4 __attribute__((ext_vector_type(4)));
typedef float  f32x4  __attribute__((ext_vector_type(4)));
typedef int    i32x4  __attribute__((ext_vector_type(4)));

#define AS_GLOBAL __attribute__((address_space(1)))
#define AS_LDS    __attribute__((address_space(3)))

__device__ __forceinline__ void gload_lds16(const void* g, void* l) {
    __builtin_amdgcn_global_load_lds((const AS_GLOBAL uint32_t*)g,
                                     (AS_LDS uint32_t*)l, 16, 0, 0);
}
__device__ __forceinline__ void cfence() { asm volatile("" ::: "memory"); }
#define BAR()    do { cfence(); __builtin_amdgcn_s_barrier(); cfence(); } while (0)
#define WAITV(n) asm volatile("s_waitcnt vmcnt(" #n ")" ::: "memory")
#define WAITL0() asm volatile("s_waitcnt lgkmcnt(0)" ::: "memory")

#define QSC 36.0f                            // q/k int8 scale
#define QDQ (1.0f / (QSC * QSC * 32.0f))     // logit dequant incl 1/sqrt(1024)

__device__ __forceinline__ int qi8(float f) {
    int q = (int)rintf(f);
    return q > 127 ? 127 : (q < -127 ? -127 : q);
}

// ---------------- convert fp32 -> bf16, 4 elems/thread ----------------
__global__ __launch_bounds__(256) void cvt_f32_to_bf16(const float* __restrict__ in,
                                                       bf16* __restrict__ out, int n4) {
    int i = blockIdx.x * 256 + threadIdx.x;
    if (i >= n4) return;
    const float4* p = (const float4*)in;
    float4 v = p[i];
    bf16x4 o;
    o[0] = (bf16)v.x; o[1] = (bf16)v.y; o[2] = (bf16)v.z; o[3] = (bf16)v.w;
    *(bf16x4*)(out + (size_t)i * 4) = o;
}

// ---- Q,K panels of QKV (bf16, ld=3072) -> int8 (scale 36), 8 elems/thread ----
__global__ __launch_bounds__(256) void cvt_qk_i8(const bf16* __restrict__ QKV,
                                                 int8_t* __restrict__ Qi8,
                                                 int8_t* __restrict__ Ki8) {
    int i = blockIdx.x * 256 + threadIdx.x;
    int base = i * 8;
    int row = base >> 11;
    int c = base & 2047;
    bf16x8 v = *(const bf16x8*)(QKV + (size_t)row * 3072 + c);
    uint32_t w0 = 0, w1 = 0;
    #pragma unroll
    for (int j = 0; j < 4; ++j) w0 |= (uint32_t)(qi8((float)v[j] * QSC) & 0xff) << (8 * j);
    #pragma unroll
    for (int j = 0; j < 4; ++j) w1 |= (uint32_t)(qi8((float)v[j + 4] * QSC) & 0xff) << (8 * j);
    int8_t* dst = (c < 1024) ? (Qi8 + (size_t)row * 1024 + c)
                             : (Ki8 + (size_t)row * 1024 + (c - 1024));
    uint2 pk; pk.x = w0; pk.y = w1;
    *(uint2*)dst = pk;
}

// ====== int8 QK^T -> bf16 E = exp(acc/41472), 16x16x64 i8 MFMA ======
// Rebuilt on gemmW's CONFLICT-FREE read geometry (r12 law: the 2-k-group 32x32
// read pattern costs exactly 4 bank-conflict cyc/ds_read_b128 [r11: 6.291456e6
// = 1024x8x192x4; r12: 1.2582912e7 = 256x64x192x4]; the 4-k-group 16x16
// pattern measures exactly 0 in the same byte layout).
// BM=BN=256, BK=128 bytes, 512 thr = 8 waves (2M x 4N), wave tile 128x64 via
// 8m x 4n 16x16 tiles. Lane frag: row = lane&15, k-bytes = (lane>>4)*16 +
// kk*64 -> slot = (kk<<2)+fg, XOR-swizzled ^(row&7) (identical to gemmW).
// C/D: col = lane&15, row = (lane>>4)*4 + i (verified family).
// 2-window schedule identical to gemmW NBH=2.
__global__ __launch_bounds__(512, 2) void gemmEi8(const int8_t* __restrict__ A,
                                                  const int8_t* __restrict__ B,
                                                  bf16* __restrict__ E,
                                                  int K, int ld, int ldc, int nbn) {
    __shared__ char smem[131072];   // A dbuf 2x32KB @0 | B dbuf 2x32KB @65536

    const int tid  = threadIdx.x;
    const int lane = tid & 63;
    const int wave = tid >> 6;
    const int wr   = wave >> 2;           // 0..1
    const int wc   = wave & 3;            // 0..3
    const int frow = lane & 15;
    const int fg   = lane >> 4;           // 0..3

    const int cpx = gridDim.x >> 3;
    const int swz = ((int)blockIdx.x & 7) * cpx + ((int)blockIdx.x >> 3);
    const int bm = swz / nbn, bn = swz % nbn;
    const int NT = K >> 7;                // 8

    const int r0 = tid >> 3;
    const int c0 = ((tid & 7) ^ (r0 & 7)) << 4;     // inv-swizzled byte col
    const int8_t* Abase = A + (size_t)(bm * 256 + r0) * ld + c0;
    const int8_t* Bbase = B + (size_t)(bn * 256 + r0) * ld + c0;

    auto stA = [&](int t, int h) {
        char* d = smem + ((t & 1) << 15) + (h << 14) + (tid << 4);
        gload_lds16(Abase + ((size_t)(h * 128)     ) * ld + t * 128, d);
        gload_lds16(Abase + ((size_t)(h * 128) + 64) * ld + t * 128, d + 8192);
    };
    auto stB = [&](int t, int h) {
        char* d = smem + 65536 + ((t & 1) << 15) + (h << 14) + (tid << 4);
        gload_lds16(Bbase + ((size_t)(h * 128)     ) * ld + t * 128, d);
        gload_lds16(Bbase + ((size_t)(h * 128) + 64) * ld + t * 128, d + 8192);
    };
    auto rdA = [&](int t, int m, int kk) -> i32x4 {   // m in [0,8)
        int r = m * 16 + frow;
        return *(const i32x4*)(smem + ((t & 1) << 15) + (wr << 14)
                + r * 128 + ((((kk << 2) + fg) ^ (frow & 7)) << 4));
    };
    auto rdB = [&](int t, int n, int kk) -> i32x4 {   // n in [0,4)
        int br = wc * 64 + n * 16 + frow;
        return *(const i32x4*)(smem + 65536 + ((t & 1) << 15) + ((br >> 7) << 14)
                + (br & 127) * 128 + ((((kk << 2) + fg) ^ (frow & 7)) << 4));
    };

    i32x4 acc[8][4] = {};
    i32x4 aLo[4][2], aHi[4][2], bLo[2][2], bHi[2][2];

#define MMQ(MO, NO, AARR, BARR) \
    _Pragma("unroll") for (int m_ = 0; m_ < 4; ++m_) \
    _Pragma("unroll") for (int n_ = 0; n_ < 2; ++n_) \
    _Pragma("unroll") for (int k_ = 0; k_ < 2; ++k_) \
        acc[m_ + MO][n_ + NO] = __builtin_amdgcn_mfma_i32_16x16x64_i8( \
            AARR[m_][k_], BARR[n_][k_], acc[m_ + MO][n_ + NO], 0, 0, 0);

    stA(0, 0); stA(0, 1);
    stB(0, 0); stB(0, 1);
    stA(1, 0); stA(1, 1);
    stB(1, 0); WAITV(6);
    BAR();

    for (int t = 0; t < NT; ++t) {
        if (t + 1 < NT) stB(t + 1, 1);
        #pragma unroll
        for (int m_ = 0; m_ < 4; ++m_) { aLo[m_][0] = rdA(t, m_, 0); aLo[m_][1] = rdA(t, m_, 1); }
        #pragma unroll
        for (int n_ = 0; n_ < 2; ++n_) { bLo[n_][0] = rdB(t, n_, 0); bLo[n_][1] = rdB(t, n_, 1); }
        #pragma unroll
        for (int n_ = 0; n_ < 2; ++n_) { bHi[n_][0] = rdB(t, 2 + n_, 0); bHi[n_][1] = rdB(t, 2 + n_, 1); }
        #pragma unroll
        for (int m_ = 0; m_ < 4; ++m_) { aHi[m_][0] = rdA(t, 4 + m_, 0); aHi[m_][1] = rdA(t, 4 + m_, 1); }
        __builtin_amdgcn_s_setprio(1);
        MMQ(0, 0, aLo, bLo);
        MMQ(0, 2, aLo, bHi);
        __builtin_amdgcn_s_setprio(0);
        WAITL0();
        BAR();
        if (t + 2 < NT) { stA(t + 2, 0); stA(t + 2, 1); stB(t + 2, 0); }
        __builtin_amdgcn_s_setprio(1);
        MMQ(4, 2, aHi, bHi);
        MMQ(4, 0, aHi, bLo);
        __builtin_amdgcn_s_setprio(0);
        if (t + 2 < NT)      { WAITV(6); }
        else if (t + 1 < NT) { WAITV(0); }
        BAR();
    }
#undef MMQ

    // epilogue: E = exp(acc * QDQ), 16x16 C/D layout: col=lane&15, row=(lane>>4)*4+i
    const size_t crow0 = (size_t)bm * 256 + wr * 128 + (fg << 2);
    const size_t ccol0 = (size_t)bn * 256 + wc * 64 + frow;
    #pragma unroll
    for (int m = 0; m < 8; ++m)
        #pragma unroll
        for (int n = 0; n < 4; ++n)
            #pragma unroll
            for (int i = 0; i < 4; ++i)
                E[(crow0 + m * 16 + i) * ldc + ccol0 + n * 16] =
                    (bf16)__expf((float)acc[m][n][i] * QDQ);
}

// ====== 2-window/K-tile bf16 GEMM (r7/r10 verified): C = A * B^T (+split-K) ======
template<typename CT, int BN, int SPLIT>
__global__ __launch_bounds__(512, 2) void gemmW(const bf16* __restrict__ A,
                                                const bf16* __restrict__ B,
                                                CT* __restrict__ C,
                                                CT* __restrict__ C2,
                                                int K, int lda, int ldb, int ldc,
                                                int nbn) {
    constexpr int NBH = BN / 128;
    constexpr int NR  = BN / 64;
    constexpr int NHF = NR / 2;
    __shared__ char smem[65536 + NBH * 32768];

    const int tid  = threadIdx.x;
    const int lane = tid & 63;
    const int wave = tid >> 6;
    const int wr   = wave >> 2;
    const int wc   = wave & 3;
    const int frow = lane & 15;
    const int fg   = lane >> 4;

    const int cpx = gridDim.x >> 3;
    const int swz = ((int)blockIdx.x & 7) * cpx + ((int)blockIdx.x >> 3);
    int id = swz, s = 0;
    if (SPLIT == 2) { s = id & 1; id >>= 1; }
    const int bm = id / nbn, bn = id % nbn;
    const int NT = K >> 6;
    const size_t koff = (size_t)s * K;
    CT* Cp = (SPLIT == 2 && s == 1) ? C2 : C;

    const int r0 = tid >> 3;
    const int c0 = ((tid & 7) ^ (r0 & 7)) << 3;
    const bf16* Abase = A + (size_t)(bm * 256 + r0) * lda + c0 + koff;
    const bf16* Bbase = B + (size_t)(bn * BN + r0) * ldb + c0 + koff;

    auto stA = [&](int t, int h) {
        char* d = smem + ((t & 1) << 15) + (h << 14) + (tid << 4);
        gload_lds16(Abase + ((size_t)(h * 128)      ) * lda + t * 64, d);
        gload_lds16(Abase + ((size_t)(h * 128) + 64 ) * lda + t * 64, d + 8192);
    };
    auto stB = [&](int t, int h) {
        char* d = smem + 65536 + (t & 1) * (NBH * 16384) + (h << 14) + (tid << 4);
        gload_lds16(Bbase + ((size_t)(h * 128)      ) * ldb + t * 64, d);
        gload_lds16(Bbase + ((size_t)(h * 128) + 64 ) * ldb + t * 64, d + 8192);
    };
    auto rdA = [&](int t, int m, int kk) -> bf16x8 {
        int r = m * 16 + frow;
        return *(const bf16x8*)(smem + ((t & 1) << 15) + (wr << 14)
                + r * 128 + ((((kk << 2) + fg) ^ (frow & 7)) << 4));
    };
    auto rdB = [&](int t, int n, int kk) -> bf16x8 {
        int br = wc * (BN / 4) + n * 16 + frow;
        return *(const bf16x8*)(smem + 65536 + (t & 1) * (NBH * 16384) + ((br >> 7) << 14)
                + (br & 127) * 128 + ((((kk << 2) + fg) ^ (frow & 7)) << 4));
    };

    f32x4 acc[8][NR] = {};
    bf16x8 aLo[4][2], aHi[4][2], bLo[NHF][2], bHi[NHF][2];

#define MMQ(MO, NO, AARR, BARR) \
    _Pragma("unroll") for (int m_ = 0; m_ < 4; ++m_) \
    _Pragma("unroll") for (int n_ = 0; n_ < NHF; ++n_) \
    _Pragma("unroll") for (int k_ = 0; k_ < 2; ++k_) \
        acc[m_ + MO][n_ + NO] = __builtin_amdgcn_mfma_f32_16x16x32_bf16( \
            AARR[m_][k_], BARR[n_][k_], acc[m_ + MO][n_ + NO], 0, 0, 0);

    stA(0, 0); stA(0, 1);
    stB(0, 0); if constexpr (NBH == 2) stB(0, 1);
    stA(1, 0); stA(1, 1);
    if constexpr (NBH == 2) { stB(1, 0); WAITV(6); } else { WAITV(4); }
    BAR();

    for (int t = 0; t < NT; ++t) {
        if (t + 1 < NT) stB(t + 1, NBH - 1);
        #pragma unroll
        for (int m_ = 0; m_ < 4; ++m_) { aLo[m_][0] = rdA(t, m_, 0); aLo[m_][1] = rdA(t, m_, 1); }
        #pragma unroll
        for (int n_ = 0; n_ < NHF; ++n_) { bLo[n_][0] = rdB(t, n_, 0); bLo[n_][1] = rdB(t, n_, 1); }
        #pragma unroll
        for (int n_ = 0; n_ < NHF; ++n_) { bHi[n_][0] = rdB(t, NHF + n_, 0); bHi[n_][1] = rdB(t, NHF + n_, 1); }
        #pragma unroll
        for (int m_ = 0; m_ < 4; ++m_) { aHi[m_][0] = rdA(t, 4 + m_, 0); aHi[m_][1] = rdA(t, 4 + m_, 1); }
        __builtin_amdgcn_s_setprio(1);
        MMQ(0, 0, aLo, bLo);
        MMQ(0, NHF, aLo, bHi);
        __builtin_amdgcn_s_setprio(0);
        WAITL0();
        BAR();
        if (t + 2 < NT) {
            stA(t + 2, 0); stA(t + 2, 1);
            if constexpr (NBH == 2) stB(t + 2, 0);
        }
        __builtin_amdgcn_s_setprio(1);
        MMQ(4, NHF, aHi, bHi);
        MMQ(4, 0, aHi, bLo);
        __builtin_amdgcn_s_setprio(0);
        if (t + 2 < NT) {
            if constexpr (NBH == 2) WAITV(6); else WAITV(4);
        } else if (t + 1 < NT) {
            WAITV(0);
        }
        BAR();
    }
#undef MMQ

    const size_t crow0 = (size_t)bm * 256 + wr * 128 + (fg << 2);
    const size_t ccol0 = (size_t)bn * BN + wc * (BN / 4) + frow;
    #pragma unroll
    for (int m = 0; m < 8; ++m)
        #pragma unroll
        for (int n = 0; n < NR; ++n)
            #pragma unroll
            for (int i = 0; i < 4; ++i)
                Cp[(crow0 + m * 16 + i) * ldc + ccol0 + n * 16] = (CT)(acc[m][n][i]);
}

// ------- rowsum of E [rows x 8192] bf16 -> inv[row] = 1/sum -------
__global__ __launch_bounds__(256) void rowsum_inv(const bf16* __restrict__ E,
                                                  float* __restrict__ inv, int cols) {
    __shared__ float red[4];
    const int tid = threadIdx.x;
    const bf16* er = E + (size_t)blockIdx.x * cols;
    float s = 0.f;
    #pragma unroll
    for (int it = 0; it < 4; ++it) {
        bf16x8 v = *(const bf16x8*)(er + it * 2048 + tid * 8);
        #pragma unroll
        for (int j = 0; j < 8; ++j) s += (float)v[j];
    }
    #pragma unroll
    for (int o = 32; o; o >>= 1) s += __shfl_xor(s, o);
    if ((tid & 63) == 0) red[tid >> 6] = s;
    __syncthreads();
    if (tid == 0) inv[blockIdx.x] = 1.0f / (red[0] + red[1] + red[2] + red[3]);
}

// ------- out[i] = (out[i] + part[i]) * inv[row], float4 -------
__global__ __launch_bounds__(256) void add_scale(float* __restrict__ out,
                                                 const float* __restrict__ part,
                                                 const float* __restrict__ inv, int n4) {
    int i = blockIdx.x * 256 + threadIdx.x;
    if (i >= n4) return;
    const float sc = inv[i >> 8];
    float4 a = ((const float4*)out)[i];
    float4 b = ((const float4*)part)[i];
    a.x = (a.x + b.x) * sc; a.y = (a.y + b.y) * sc;
    a.z = (a.z + b.z) * sc; a.w = (a.w + b.w) * sc;
    ((float4*)out)[i] = a;
}

// ------- bf16 transpose with input row stride: VT[c][r] = V[r*ld + c] -------
__global__ __launch_bounds__(256) void transpose_bf16(const ushort* __restrict__ V,
                                                      ushort* __restrict__ VT,
                                                      int R, int ld) {
    __shared__ ushort tile[32][33];
    const int tx = threadIdx.x, ty = threadIdx.y;
    const int r0 = blockIdx.y * 32, c0 = blockIdx.x * 32;
    #pragma unroll
    for (int i = 0; i < 32; i += 8)
        tile[ty + i][tx] = V[(size_t)(r0 + ty + i) * ld + c0 + tx];
    __syncthreads();
    #pragma unroll
    for (int i = 0; i < 32; i += 8)
        VT[(size_t)(c0 + ty + i) * R + r0 + tx] = tile[tx][ty + i];
}

extern "C" void kernel_launch(void* const* d_in, const int* in_sizes, int n_in,
                              void* d_out, int out_size, void* d_ws, size_t ws_size,
                              hipStream_t stream) {
    const float* h  = (const float*)d_in[0];
    const float* wq = (const float*)d_in[1];
    const float* wk = (const float*)d_in[2];
    const float* wv = (const float*)d_in[3];
    float* out = (float*)d_out;

    char* ws = (char*)d_ws;
    bf16*   h_bf = (bf16*)(ws);                         // 16 MB [8192 x 1024]
    bf16*   wcat = (bf16*)(ws + (16ull << 20));         //  6 MB [3072 x 1024]
    bf16*   QKV  = (bf16*)(ws + (22ull << 20));         // 48 MB [8192 x 3072]
    bf16*   VT   = (bf16*)(ws + (70ull << 20));         // 16 MB [1024 x 8192]
    bf16*   E    = (bf16*)(ws + (86ull << 20));         // 128 MB [8192 x 8192]
    int8_t* Qi8  = (int8_t*)(ws);                       //  8 MB (h_bf dead post-QKV)
    int8_t* Ki8  = (int8_t*)(ws + (8ull << 20));        //  8 MB
    float*  Pv   = (float*)(ws);                        // 32 MB (Qi8/Ki8 dead by PV)
    float*  invp = (float*)(ws + (33ull << 20));        // 32 KB (QKV dead by rowsum)

    // 1) inputs -> bf16 (weights concatenated [3072,1024])
    cvt_f32_to_bf16<<<8192, 256, 0, stream>>>(h,  h_bf, (8192 * 1024) / 4);
    cvt_f32_to_bf16<<<1024, 256, 0, stream>>>(wq, wcat,               (1024 * 1024) / 4);
    cvt_f32_to_bf16<<<1024, 256, 0, stream>>>(wk, wcat + 1024 * 1024, (1024 * 1024) / 4);
    cvt_f32_to_bf16<<<1024, 256, 0, stream>>>(wv, wcat + 2048 * 1024, (1024 * 1024) / 4);

    // 2) QKV = h @ wcat^T : [8192 x 3072], bf16 GEMM, grid 384
    gemmW<bf16, 256, 1><<<384, 512, 0, stream>>>(h_bf, wcat, QKV, nullptr,
                                                 1024, 1024, 1024, 3072, 12);

    // 3) Q,K -> int8 (scale 36)
    cvt_qk_i8<<<8192, 256, 0, stream>>>(QKV, Qi8, Ki8);

    // 4) VT = V^T, bf16 (V = QKV[:, 2048:3072])
    transpose_bf16<<<dim3(32, 256), dim3(32, 8), 0, stream>>>(
        (const ushort*)(QKV + 2048), (ushort*)VT, 8192, 3072);

    // 5) E = exp((Qi8 . Ki8)/41472), 16x16x64 i8 MFMA (conflict-free reads), grid 1024
    gemmEi8<<<1024, 512, 0, stream>>>(Qi8, Ki8, E, 1024, 1024, 8192, 32);

    // 6) inv[row] = 1 / rowsum(E)
    rowsum_inv<<<8192, 256, 0, stream>>>(E, invp, 8192);

    // 7) P = E @ VT^T, 16x16x32 bf16 (r10-proven), split-K=2, grid 256
    gemmW<float, 256, 2><<<256, 512, 0, stream>>>(E, VT, out, Pv,
                                                  4096, 8192, 8192, 1024, 4);

    // 8) out = (P0 + P1) * inv[row]
    add_scale<<<8192, 256, 0, stream>>>(out, Pv, invp, (8192 * 1024) / 4);
}